// Round 8
// baseline (3623.782 us; speedup 1.0000x reference)
//
#include <hip/hip_runtime.h>

#define Hh 1024
#define NBATCH 128
#define TSTEPS 256
#define DOUT 1024
#define SLOT (NBATCH * Hh)
#define NITER 262  // 256 lstm steps + 6 fc drain iterations

typedef _Float16 half8 __attribute__((ext_vector_type(8)));
typedef float floatx4 __attribute__((ext_vector_type(4)));

__device__ __forceinline__ float fast_sigmoid(float x) {
  float e = __expf(-x);
  return __builtin_amdgcn_rcpf(1.0f + e);
}
__device__ __forceinline__ float fast_tanh(float x) {
  x = fminf(15.0f, fmaxf(-15.0f, x));
  float e = __expf(-2.0f * x);
  return 1.0f - 2.0f * e * __builtin_amdgcn_rcpf(1.0f + e);
}

// Convert weights to f16, build W_sum = W_ih + W_hh, b_sum = b_ih + b_hh,
// stage hT as f16 into hs slot 0, zero flags (256) + per-XCD counters (8).
__global__ void prep_kernel(const float* __restrict__ W_ih, const float* __restrict__ W_hh,
                            const float* __restrict__ W_fc, const float* __restrict__ b_ih,
                            const float* __restrict__ b_hh, const float* __restrict__ hT,
                            _Float16* __restrict__ w_ih_h, _Float16* __restrict__ w_sum_h,
                            _Float16* __restrict__ w_fc_h, float* __restrict__ b_sum,
                            _Float16* __restrict__ hs0, unsigned* __restrict__ flags) {
  int i0 = blockIdx.x * blockDim.x + threadIdx.x;
  int stride = gridDim.x * blockDim.x;
  for (int i = i0; i < 4096 * 1024; i += stride) {
    float a = W_ih[i];
    w_ih_h[i] = (_Float16)a;
    w_sum_h[i] = (_Float16)(a + W_hh[i]);
  }
  for (int i = i0; i < 1024 * 1024; i += stride) w_fc_h[i] = (_Float16)W_fc[i];
  for (int i = i0; i < 4096; i += stride) b_sum[i] = b_ih[i] + b_hh[i];
  for (int i = i0; i < NBATCH * Hh; i += stride) hs0[i] = (_Float16)hT[i];
  for (int i = i0; i < 512; i += stride) flags[i] = 0;  // flags[256] + xcd_ctr[8]
}

// Fused persistent kernel: 256 WGs (one per CU), 512 threads = 8 waves
// (2/SIMD, VGPR-capped at 256 via launch_bounds).
//   waves 0-3: LSTM, byte-exact round-6 structure (964us proven): two
//     __syncthreads per step, per-WG flag by tid 0 after the vmcnt-draining
//     barrier, per-wave fine-grained poll of 8 producer WG flags. Only
//     deltas: flag also stored for the last step (fc needs flag 256), and
//     6 trailing barrier-only iterations (barrier-count parity with fc).
//   waves 4-7: FC GEMM in the lstm's idle shadow. fc wave fwi processes
//     slot u === fwi (mod 4) across iterations u+2..u+5 (one K=256 chunk
//     per iteration, 16 MFMAs, acc in regs), polling all-32 group flags
//     >= u only at chunk 0. The 2-iteration lag means the poll is almost
//     always already satisfied -> fc never stiffens the barrier (fc
//     pre-barrier work ~2K cy << lstm's ~7K cy). A-reads are the group's
//     own 16 h-rows = the exact bytes lstm waves pulled into this XCD's
//     L2 two iterations earlier (L2-hot); W_fc block (64KB/WG) L2-resident.
//   Deadlock-free: fc poll target at iter t is <= t-2; all flags >= t-2
//     holds once all WGs completed iter t-3 (strict induction). Both
//     personas execute exactly 262 barrier pairs.
__global__ __launch_bounds__(512, 2) void lstm_kernel(
    const _Float16* __restrict__ w_ih_h, const _Float16* __restrict__ w_sum_h,
    const float* __restrict__ b_sum, _Float16* __restrict__ hs,
    unsigned* __restrict__ flags, const _Float16* __restrict__ w_fc,
    const float* __restrict__ b_fc, float* __restrict__ out) {
  unsigned* xcd_ctr = flags + 256;
  const int tid = threadIdx.x;
  const int wave8 = tid >> 6;
  const int lane = tid & 63;
  const int l15 = lane & 15;
  const int quad = lane >> 4;

  __shared__ unsigned role_sh;
  {
    unsigned xcd;
    asm volatile("s_getreg_b32 %0, hwreg(HW_REG_XCC_ID)" : "=s"(xcd));
    if (tid == 0) role_sh = (xcd << 8) | atomicAdd(&xcd_ctr[xcd], 1u);
  }
  __syncthreads();
  const int g = role_sh >> 8;    // physical XCD == n-group
  const int jb = role_sh & 255;  // 0..31 within the XCD
  const int n0 = g * 16;
  const int j0 = jb * 32;
  unsigned* gflags = flags + g * 32;

  __shared__ float2 part[4][2][4][2][64];  // [src][ct][gate][rpair][lane] = 32KB

  if (wave8 < 4) {
    // ---------------- LSTM persona (round-6 verbatim) ----------------
    const int wave = wave8;
    const int kbase = wave * 256;
    const int oc = wave >> 1;
    const int rp = wave & 1;
    unsigned* pollp = gflags + wave * 8 + (lane & 7);

    float bias[4];
#pragma unroll
    for (int gt = 0; gt < 4; ++gt) bias[gt] = b_sum[gt * 1024 + j0 + oc * 16 + l15];

    half8 B[4][2][8];
    float cst[2] = {0.0f, 0.0f};

    auto load_B = [&](const _Float16* w) {
#pragma unroll
      for (int gt = 0; gt < 4; ++gt)
#pragma unroll
        for (int ct = 0; ct < 2; ++ct) {
          const _Float16* p =
              w + (size_t)(gt * 1024 + j0 + ct * 16 + l15) * Hh + kbase + quad * 8;
#pragma unroll
          for (int ks = 0; ks < 8; ++ks) B[gt][ct][ks] = *(const half8*)(p + ks * 32);
        }
    };

    auto poll = [&](int tgt) {
      while (1) {
        unsigned v = __hip_atomic_load(pollp, __ATOMIC_RELAXED, __HIP_MEMORY_SCOPE_AGENT);
        if (__all((int)(v >= (unsigned)tgt))) break;
      }
    };

    auto do_step = [&](const _Float16* hsrc, _Float16* hdst, int sready) {
      poll(sready);
      floatx4 acc[2][4] = {};
      const _Float16* ap = hsrc + (size_t)(n0 + l15) * Hh + kbase + quad * 8;
#pragma unroll
      for (int ks = 0; ks < 8; ++ks) {
        half8 a = *(const half8*)(ap + ks * 32);
#pragma unroll
        for (int ct = 0; ct < 2; ++ct)
#pragma unroll
          for (int gt = 0; gt < 4; ++gt)
            acc[ct][gt] =
                __builtin_amdgcn_mfma_f32_16x16x32_f16(a, B[gt][ct][ks], acc[ct][gt], 0, 0, 0);
      }
#pragma unroll
      for (int ct = 0; ct < 2; ++ct)
#pragma unroll
        for (int gt = 0; gt < 4; ++gt) {
          float2 lo, hi;
          lo.x = acc[ct][gt][0]; lo.y = acc[ct][gt][1];
          hi.x = acc[ct][gt][2]; hi.y = acc[ct][gt][3];
          part[wave][ct][gt][0][lane] = lo;
          part[wave][ct][gt][1][lane] = hi;
        }
      __syncthreads();

      float gv[4][2];
#pragma unroll
      for (int gt = 0; gt < 4; ++gt) {
        float2 s = part[0][oc][gt][rp][lane];
#pragma unroll
        for (int src = 1; src < 4; ++src) {
          float2 p = part[src][oc][gt][rp][lane];
          s.x += p.x; s.y += p.y;
        }
        gv[gt][0] = s.x + bias[gt];
        gv[gt][1] = s.y + bias[gt];
      }
#pragma unroll
      for (int rr = 0; rr < 2; ++rr) {
        float ig = fast_sigmoid(gv[0][rr]);
        float fg = fast_sigmoid(gv[1][rr]);
        float gg = fast_tanh(gv[2][rr]);
        float og = fast_sigmoid(gv[3][rr]);
        float c = fg * cst[rr] + ig * gg;
        cst[rr] = c;
        float h = og * fast_tanh(c);
        int row = n0 + quad * 4 + rp * 2 + rr;
        _Float16 hv = (_Float16)h;
        unsigned short ub;
        __builtin_memcpy(&ub, &hv, 2);
        __hip_atomic_store((unsigned short*)(hdst + (size_t)row * Hh + j0 + oc * 16 + l15),
                           ub, __ATOMIC_RELAXED, __HIP_MEMORY_SCOPE_AGENT);
      }
      __syncthreads();  // drains vmcnt(0): h stores at coherent point
      if (tid == 0) {
        __hip_atomic_store(&gflags[jb], (unsigned)(sready + 1), __ATOMIC_RELAXED,
                           __HIP_MEMORY_SCOPE_AGENT);
      }
    };

    load_B(w_ih_h);
    do_step(hs, hs + SLOT, 0);
    load_B(w_sum_h);
    for (int s = 1; s < TSTEPS; ++s)
      do_step(hs + (size_t)s * SLOT, hs + (size_t)(s + 1) * SLOT, s);
    // barrier-parity drain with fc persona
    for (int t = TSTEPS; t < NITER; ++t) {
      __syncthreads();
      __syncthreads();
    }
  } else {
    // ---------------- FC persona ----------------
    const int fwi = wave8 - 4;  // 0..3: handles slots u === fwi (mod 4)
    const int d0 = j0;          // this WG's 32 d-cols
    unsigned* fpoll = gflags + (lane & 31);
    float bfc0 = b_fc[d0 + l15];
    float bfc1 = b_fc[d0 + 16 + l15];
    floatx4 acc0 = {}, acc1 = {};

    for (int t = 0; t < NITER; ++t) {
      int dd = t - 2 - fwi;
      int chunk = dd & 3;
      int uu = t - 2 - chunk;
      bool active = (dd >= 0) && (uu >= 1) && (uu <= TSTEPS);
      if (active) {
        if (chunk == 0) {
          acc0 = (floatx4){0.f, 0.f, 0.f, 0.f};
          acc1 = (floatx4){0.f, 0.f, 0.f, 0.f};
          while (1) {
            unsigned v = __hip_atomic_load(fpoll, __ATOMIC_RELAXED, __HIP_MEMORY_SCOPE_AGENT);
            if (__all((int)(v >= (unsigned)uu))) break;
          }
          asm volatile("" ::: "memory");  // keep A-loads below poll exit
        }
        const _Float16* ap =
            hs + (size_t)uu * SLOT + (size_t)(n0 + l15) * Hh + chunk * 256 + quad * 8;
        const _Float16* bp0 = w_fc + (size_t)(d0 + l15) * Hh + chunk * 256 + quad * 8;
        const _Float16* bp1 = bp0 + (size_t)16 * Hh;
#pragma unroll
        for (int ks = 0; ks < 8; ++ks) {
          half8 a = *(const half8*)(ap + ks * 32);
          half8 b0 = *(const half8*)(bp0 + ks * 32);
          half8 b1 = *(const half8*)(bp1 + ks * 32);
          acc0 = __builtin_amdgcn_mfma_f32_16x16x32_f16(a, b0, acc0, 0, 0, 0);
          acc1 = __builtin_amdgcn_mfma_f32_16x16x32_f16(a, b1, acc1, 0, 0, 0);
        }
      }
      __syncthreads();
      __syncthreads();
      if (active && chunk == 3) {
        // out[n, uu-1, d]: rows n0 + quad*4 + r, d-cols d0 + {l15, 16+l15}
#pragma unroll
        for (int r = 0; r < 4; ++r) {
          size_t o = ((size_t)(n0 + quad * 4 + r) * TSTEPS + (uu - 1)) * DOUT + d0 + l15;
          out[o] = acc0[r] + bfc0;
          out[o + 16] = acc1[r] + bfc1;
        }
      }
    }
  }
}

extern "C" void kernel_launch(void* const* d_in, const int* in_sizes, int n_in,
                              void* d_out, int out_size, void* d_ws, size_t ws_size,
                              hipStream_t stream) {
  const float* hT   = (const float*)d_in[0];
  const float* W_ih = (const float*)d_in[1];
  const float* W_hh = (const float*)d_in[2];
  const float* b_ih = (const float*)d_in[3];
  const float* b_hh = (const float*)d_in[4];
  const float* W_fc = (const float*)d_in[5];
  const float* b_fc = (const float*)d_in[6];
  float* out = (float*)d_out;

  char* ws = (char*)d_ws;
  unsigned* flags   = (unsigned*)ws;                    // flags[256] + xcd_ctr[8]
  float* b_sum      = (float*)(ws + 4096);              // 16KB
  _Float16* w_ih_h  = (_Float16*)(ws + 65536);          // 8MB
  _Float16* w_sum_h = w_ih_h + (size_t)4096 * 1024;     // 8MB
  _Float16* w_fc_h  = w_sum_h + (size_t)4096 * 1024;    // 2MB
  _Float16* hs      = w_fc_h + (size_t)1024 * 1024;     // 257 * 256KB = 67.3MB

  prep_kernel<<<4096, 256, 0, stream>>>(W_ih, W_hh, W_fc, b_ih, b_hh, hT,
                                        w_ih_h, w_sum_h, w_fc_h, b_sum, hs, flags);
  lstm_kernel<<<256, 512, 0, stream>>>(w_ih_h, w_sum_h, b_sum, hs, flags,
                                       w_fc_h, b_fc, out);
}

// Round 9
// 1936.733 us; speedup vs baseline: 1.8711x; 1.8711x over previous
//
#include <hip/hip_runtime.h>

#define Hh 1024
#define NBATCH 128
#define TSTEPS 256
#define DOUT 1024
#define SLOT (NBATCH * Hh)

typedef _Float16 half8 __attribute__((ext_vector_type(8)));
typedef float floatx4 __attribute__((ext_vector_type(4)));

__device__ __forceinline__ float fast_sigmoid(float x) {
  float e = __expf(-x);
  return __builtin_amdgcn_rcpf(1.0f + e);
}
__device__ __forceinline__ float fast_tanh(float x) {
  x = fminf(15.0f, fmaxf(-15.0f, x));
  float e = __expf(-2.0f * x);
  return 1.0f - 2.0f * e * __builtin_amdgcn_rcpf(1.0f + e);
}

// Convert weights to f16, build W_sum = W_ih + W_hh, b_sum = b_ih + b_hh,
// stage hT as f16 into hs slot 0, zero flags (256) + per-XCD counters (8).
__global__ void prep_kernel(const float* __restrict__ W_ih, const float* __restrict__ W_hh,
                            const float* __restrict__ W_fc, const float* __restrict__ b_ih,
                            const float* __restrict__ b_hh, const float* __restrict__ hT,
                            _Float16* __restrict__ w_ih_h, _Float16* __restrict__ w_sum_h,
                            _Float16* __restrict__ w_fc_h, float* __restrict__ b_sum,
                            _Float16* __restrict__ hs0, unsigned* __restrict__ flags) {
  int i0 = blockIdx.x * blockDim.x + threadIdx.x;
  int stride = gridDim.x * blockDim.x;
  for (int i = i0; i < 4096 * 1024; i += stride) {
    float a = W_ih[i];
    w_ih_h[i] = (_Float16)a;
    w_sum_h[i] = (_Float16)(a + W_hh[i]);
  }
  for (int i = i0; i < 1024 * 1024; i += stride) w_fc_h[i] = (_Float16)W_fc[i];
  for (int i = i0; i < 4096; i += stride) b_sum[i] = b_ih[i] + b_hh[i];
  for (int i = i0; i < NBATCH * Hh; i += stride) hs0[i] = (_Float16)hT[i];
  for (int i = i0; i < 512; i += stride) flags[i] = 0;  // flags[256] + xcd_ctr[8]
}

// Fused persistent kernel: 256 WGs (one per CU), 512 threads = 8 waves
// (2/SIMD). ALL waves run the lstm persona at K=128 each (weights = 128
// regs/lane, total budget ~210 <= 256 cap -- v8's spill disaster was the
// 256-reg weight block at a 256 cap). Sync semantics are byte-identical
// to the proven v6 discipline: two __syncthreads per step, drain-then-
// per-WG-flag by tid 0, per-wave fine poll (now 4 producers per wave).
//
// fc fusion by TIME-MULTIPLEXING: at step s, wave (s&7) computes the fc
// output tile for slot s (16 rows x 32 d-cols, K=1024, ~1500cy) AFTER the
// flag store -- inside the ~6500cy of poll slack, off the producer->
// consumer latency chain. Safety: the 8 waves' polls at step s jointly
// cover all 32 group flags >= s, so after barrier 1 slot s is fully
// written+drained; fc reads it after barrier 2. Slot 256 in an epilogue
// (wave 0 polls all 32 flags >= 256). Slots 1..256 each covered once.
__global__ __launch_bounds__(512, 2) void lstm_kernel(
    const _Float16* __restrict__ w_ih_h, const _Float16* __restrict__ w_sum_h,
    const float* __restrict__ b_sum, _Float16* __restrict__ hs,
    unsigned* __restrict__ flags, const _Float16* __restrict__ w_fc,
    const float* __restrict__ b_fc, float* __restrict__ out) {
  unsigned* xcd_ctr = flags + 256;
  const int tid = threadIdx.x;
  const int wave = tid >> 6;  // 0..7
  const int lane = tid & 63;
  const int l15 = lane & 15;
  const int quad = lane >> 4;

  __shared__ unsigned role_sh;
  {
    unsigned xcd;
    asm volatile("s_getreg_b32 %0, hwreg(HW_REG_XCC_ID)" : "=s"(xcd));
    if (tid == 0) role_sh = (xcd << 8) | atomicAdd(&xcd_ctr[xcd], 1u);
  }
  __syncthreads();
  const int g = role_sh >> 8;    // physical XCD == n-group
  const int jb = role_sh & 255;  // 0..31 within the XCD
  const int n0 = g * 16;
  const int j0 = jb * 32;
  const int kbase = wave * 128;          // this wave's K-range [kbase, kbase+128)
  const int oc = wave & 1;               // 16-col half of the 32-col j-block
  const int rp = (wave >> 1) & 1;        // accumulator reg-pair
  const int rr = (wave >> 2) & 1;        // element within the pair
  unsigned* gflags = flags + g * 32;
  // wave's K-range covered by producers jb' in [4*wave, 4*wave+4)
  unsigned* pollp = gflags + wave * 4 + (lane & 3);

  __shared__ float2 part[8][2][4][2][64];  // [src][ct][gate][rpair][lane] = 64KB

  float bias[4];
#pragma unroll
  for (int gt = 0; gt < 4; ++gt) bias[gt] = b_sum[gt * 1024 + j0 + oc * 16 + l15];
  const float bfc0 = b_fc[j0 + l15];
  const float bfc1 = b_fc[j0 + 16 + l15];

  half8 B[4][2][4];   // 128 regs of resident lstm weights per lane
  float cst = 0.0f;   // persistent cell state (1 element/lane)

  auto load_B = [&](const _Float16* w) {
#pragma unroll
    for (int gt = 0; gt < 4; ++gt)
#pragma unroll
      for (int ct = 0; ct < 2; ++ct) {
        const _Float16* p =
            w + (size_t)(gt * 1024 + j0 + ct * 16 + l15) * Hh + kbase + quad * 8;
#pragma unroll
        for (int ks = 0; ks < 4; ++ks) B[gt][ct][ks] = *(const half8*)(p + ks * 32);
      }
  };

  auto poll = [&](int tgt) {
    while (1) {
      unsigned v = __hip_atomic_load(pollp, __ATOMIC_RELAXED, __HIP_MEMORY_SCOPE_AGENT);
      if (__all((int)(v >= (unsigned)tgt))) break;
    }
  };

  // fc for slot u (u in 1..256): out[n0..+16, u-1, j0..+32]
  auto fc_slot = [&](int u) {
    floatx4 f0 = {}, f1 = {};
    const _Float16* ap = hs + (size_t)u * SLOT + (size_t)(n0 + l15) * Hh + quad * 8;
    const _Float16* bp0 = w_fc + (size_t)(j0 + l15) * Hh + quad * 8;
    const _Float16* bp1 = bp0 + (size_t)16 * Hh;
#pragma unroll 4
    for (int kk = 0; kk < Hh; kk += 32) {
      half8 a = *(const half8*)(ap + kk);
      half8 b0 = *(const half8*)(bp0 + kk);
      half8 b1 = *(const half8*)(bp1 + kk);
      f0 = __builtin_amdgcn_mfma_f32_16x16x32_f16(a, b0, f0, 0, 0, 0);
      f1 = __builtin_amdgcn_mfma_f32_16x16x32_f16(a, b1, f1, 0, 0, 0);
    }
#pragma unroll
    for (int r = 0; r < 4; ++r) {
      size_t o = ((size_t)(n0 + quad * 4 + r) * TSTEPS + (u - 1)) * DOUT + j0 + l15;
      out[o] = f0[r] + bfc0;
      out[o + 16] = f1[r] + bfc1;
    }
  };

  auto do_step = [&](const _Float16* hsrc, _Float16* hdst, int s) {
    poll(s);  // wait only for this wave's 4 producers
    floatx4 acc[2][4] = {};
    const _Float16* ap = hsrc + (size_t)(n0 + l15) * Hh + kbase + quad * 8;
#pragma unroll
    for (int ks = 0; ks < 4; ++ks) {
      half8 a = *(const half8*)(ap + ks * 32);
#pragma unroll
      for (int ct = 0; ct < 2; ++ct)
#pragma unroll
        for (int gt = 0; gt < 4; ++gt)
          acc[ct][gt] =
              __builtin_amdgcn_mfma_f32_16x16x32_f16(a, B[gt][ct][ks], acc[ct][gt], 0, 0, 0);
    }
#pragma unroll
    for (int ct = 0; ct < 2; ++ct)
#pragma unroll
      for (int gt = 0; gt < 4; ++gt) {
        float2 lo, hi;
        lo.x = acc[ct][gt][0]; lo.y = acc[ct][gt][1];
        hi.x = acc[ct][gt][2]; hi.y = acc[ct][gt][3];
        part[wave][ct][gt][0][lane] = lo;
        part[wave][ct][gt][1][lane] = hi;
      }
    __syncthreads();

    float gv[4];
#pragma unroll
    for (int gt = 0; gt < 4; ++gt) {
      float s2 = bias[gt];
#pragma unroll
      for (int src = 0; src < 8; ++src) {
        float2 p = part[src][oc][gt][rp][lane];
        s2 += rr ? p.y : p.x;
      }
      gv[gt] = s2;
    }
    {
      float ig = fast_sigmoid(gv[0]);
      float fg = fast_sigmoid(gv[1]);
      float gg = fast_tanh(gv[2]);
      float og = fast_sigmoid(gv[3]);
      float c = fg * cst + ig * gg;
      cst = c;
      float h = og * fast_tanh(c);
      int row = n0 + quad * 4 + rp * 2 + rr;
      _Float16 hv = (_Float16)h;
      unsigned short ub;
      __builtin_memcpy(&ub, &hv, 2);
      // agent write-through store (v6-proven): at coherent point once vmcnt
      // retires; the following __syncthreads drains vmcnt.
      __hip_atomic_store((unsigned short*)(hdst + (size_t)row * Hh + j0 + oc * 16 + l15),
                         ub, __ATOMIC_RELAXED, __HIP_MEMORY_SCOPE_AGENT);
    }
    __syncthreads();  // drain: all 8 waves' h stores at coherent point
    if (tid == 0) {
      __hip_atomic_store(&gflags[jb], (unsigned)(s + 1), __ATOMIC_RELAXED,
                         __HIP_MEMORY_SCOPE_AGENT);
    }
    // fc in the poll slack, off the producer->consumer chain. Slot s is
    // fully ready: all 32 group flags >= s were observed before barrier 1.
    if (s >= 1 && (s & 7) == wave) fc_slot(s);
  };

  // Step 0: x = hT, hx = 0  =>  gates = hT @ W_ih^T + b_sum
  load_B(w_ih_h);
  do_step(hs, hs + SLOT, 0);
  // Steps 1..255: x = hx = h  =>  gates = h @ (W_ih+W_hh)^T + b_sum
  load_B(w_sum_h);
  for (int s = 1; s < TSTEPS; ++s)
    do_step(hs + (size_t)s * SLOT, hs + (size_t)(s + 1) * SLOT, s);

  // Epilogue: slot 256 (produced by step 255, flag value 256).
  if (wave == 0) {
    while (1) {
      unsigned v = __hip_atomic_load(&gflags[lane & 31], __ATOMIC_RELAXED,
                                     __HIP_MEMORY_SCOPE_AGENT);
      if (__all((int)(v >= (unsigned)TSTEPS))) break;
    }
    fc_slot(TSTEPS);
  }
}

extern "C" void kernel_launch(void* const* d_in, const int* in_sizes, int n_in,
                              void* d_out, int out_size, void* d_ws, size_t ws_size,
                              hipStream_t stream) {
  const float* hT   = (const float*)d_in[0];
  const float* W_ih = (const float*)d_in[1];
  const float* W_hh = (const float*)d_in[2];
  const float* b_ih = (const float*)d_in[3];
  const float* b_hh = (const float*)d_in[4];
  const float* W_fc = (const float*)d_in[5];
  const float* b_fc = (const float*)d_in[6];
  float* out = (float*)d_out;

  char* ws = (char*)d_ws;
  unsigned* flags   = (unsigned*)ws;                    // flags[256] + xcd_ctr[8]
  float* b_sum      = (float*)(ws + 4096);              // 16KB
  _Float16* w_ih_h  = (_Float16*)(ws + 65536);          // 8MB
  _Float16* w_sum_h = w_ih_h + (size_t)4096 * 1024;     // 8MB
  _Float16* w_fc_h  = w_sum_h + (size_t)4096 * 1024;    // 2MB
  _Float16* hs      = w_fc_h + (size_t)1024 * 1024;     // 257 * 256KB = 67.3MB

  prep_kernel<<<4096, 256, 0, stream>>>(W_ih, W_hh, W_fc, b_ih, b_hh, hT,
                                        w_ih_h, w_sum_h, w_fc_h, b_sum, hs, flags);
  lstm_kernel<<<256, 512, 0, stream>>>(w_ih_h, w_sum_h, b_sum, hs, flags,
                                       w_fc_h, b_fc, out);
}

// Round 10
// 984.910 us; speedup vs baseline: 3.6793x; 1.9664x over previous
//
#include <hip/hip_runtime.h>

#define Hh 1024
#define NBATCH 128
#define TSTEPS 256
#define DOUT 1024
#define SLOT (NBATCH * Hh)

typedef _Float16 half8 __attribute__((ext_vector_type(8)));
typedef float floatx4 __attribute__((ext_vector_type(4)));

__device__ __forceinline__ float fast_sigmoid(float x) {
  float e = __expf(-x);
  return __builtin_amdgcn_rcpf(1.0f + e);
}
__device__ __forceinline__ float fast_tanh(float x) {
  x = fminf(15.0f, fmaxf(-15.0f, x));
  float e = __expf(-2.0f * x);
  return 1.0f - 2.0f * e * __builtin_amdgcn_rcpf(1.0f + e);
}

// Convert weights to f16, build W_sum = W_ih + W_hh, b_sum = b_ih + b_hh,
// stage hT as f16 into hs slot 0, zero flags (256) + per-XCD counters (8).
__global__ void prep_kernel(const float* __restrict__ W_ih, const float* __restrict__ W_hh,
                            const float* __restrict__ W_fc, const float* __restrict__ b_ih,
                            const float* __restrict__ b_hh, const float* __restrict__ hT,
                            _Float16* __restrict__ w_ih_h, _Float16* __restrict__ w_sum_h,
                            _Float16* __restrict__ w_fc_h, float* __restrict__ b_sum,
                            _Float16* __restrict__ hs0, unsigned* __restrict__ flags) {
  int i0 = blockIdx.x * blockDim.x + threadIdx.x;
  int stride = gridDim.x * blockDim.x;
  for (int i = i0; i < 4096 * 1024; i += stride) {
    float a = W_ih[i];
    w_ih_h[i] = (_Float16)a;
    w_sum_h[i] = (_Float16)(a + W_hh[i]);
  }
  for (int i = i0; i < 1024 * 1024; i += stride) w_fc_h[i] = (_Float16)W_fc[i];
  for (int i = i0; i < 4096; i += stride) b_sum[i] = b_ih[i] + b_hh[i];
  for (int i = i0; i < NBATCH * Hh; i += stride) hs0[i] = (_Float16)hT[i];
  for (int i = i0; i < 512; i += stride) flags[i] = 0;  // flags[256] + xcd_ctr[8]
}

// Fused persistent kernel: 256 WGs (one per CU), 512 threads = 8 waves.
// All waves run the lstm persona at K=128 (v9-proven: 8-wave base step
// time == 4-wave baseline). Sync = v6-proven discipline verbatim.
//
// fc fusion v10: DISTRIBUTED, ZERO EXTRA A-LOADS. At step s, wave w's
// register A-fragments a[ks] (slot s, rows n0..n0+16, K in [128w,128w+128))
// are exactly the fc A-operand chunk for that K-range. Each wave keeps 32
// extra weight regs (Bfc = w_fc rows j0..j0+32, its K-chunk) and adds 2 fc
// MFMAs per ks (8/step, ~40cy) reusing a. K=128 partials -> 16KB LDS;
// after barrier 1 each of the 512 threads reduces 8 partials and stores
// ONE out dword (coalesced). Per-step cost ~300-500cy inside the existing
// structure -- no serialized fc phase (v9's mistake: one wave doing a
// latency-bound K=1024 GEMM serially extended every step by ~3.4us).
// Slot 256 via epilogue: poll all 32 flags >= 256, same pattern.
// Race-safety: fcpart writes(s+1) occur after barrier2(s); reads(s)
// before barrier2(s) -- the v6 two-barrier argument.
__global__ __launch_bounds__(512, 2) void lstm_kernel(
    const _Float16* __restrict__ w_ih_h, const _Float16* __restrict__ w_sum_h,
    const float* __restrict__ b_sum, _Float16* __restrict__ hs,
    unsigned* __restrict__ flags, const _Float16* __restrict__ w_fc,
    const float* __restrict__ b_fc, float* __restrict__ out) {
  unsigned* xcd_ctr = flags + 256;
  const int tid = threadIdx.x;
  const int wave = tid >> 6;  // 0..7
  const int lane = tid & 63;
  const int l15 = lane & 15;
  const int quad = lane >> 4;

  __shared__ unsigned role_sh;
  {
    unsigned xcd;
    asm volatile("s_getreg_b32 %0, hwreg(HW_REG_XCC_ID)" : "=s"(xcd));
    if (tid == 0) role_sh = (xcd << 8) | atomicAdd(&xcd_ctr[xcd], 1u);
  }
  __syncthreads();
  const int g = role_sh >> 8;    // physical XCD == n-group
  const int jb = role_sh & 255;  // 0..31 within the XCD
  const int n0 = g * 16;
  const int j0 = jb * 32;
  const int kbase = wave * 128;      // this wave's K-range
  const int oc = wave & 1;           // 16-col half of the 32-col j-block
  const int rp = (wave >> 1) & 1;    // accumulator reg-pair
  const int rr = (wave >> 2) & 1;    // element within the pair
  unsigned* gflags = flags + g * 32;
  unsigned* pollp = gflags + wave * 4 + (lane & 3);  // 4 producers cover K-range

  __shared__ float2 part[8][2][4][2][64];   // 64KB lstm partials
  __shared__ floatx4 fcpart[8][2][64];      // 16KB fc partials

  float bias[4];
#pragma unroll
  for (int gt = 0; gt < 4; ++gt) bias[gt] = b_sum[gt * 1024 + j0 + oc * 16 + l15];

  // fc reduce role: thread tid owns out element (row fc_row, col fc_col)
  const int fc_col = tid & 31;
  const int fc_row = tid >> 5;  // 0..15
  const float bfc = b_fc[j0 + fc_col];
  const int fc_half = fc_col >> 4;
  const int fc_lsrc = (fc_row >> 2) * 16 + (fc_col & 15);
  const int fc_comp = fc_row & 3;

  half8 B[4][2][4];   // 128 regs lstm weights
  half8 Bfc[2][4];    // 32 regs fc weights (this wave's K-chunk)
  float cst = 0.0f;   // persistent cell state

  auto load_B = [&](const _Float16* w) {
#pragma unroll
    for (int gt = 0; gt < 4; ++gt)
#pragma unroll
      for (int ct = 0; ct < 2; ++ct) {
        const _Float16* p =
            w + (size_t)(gt * 1024 + j0 + ct * 16 + l15) * Hh + kbase + quad * 8;
#pragma unroll
        for (int ks = 0; ks < 4; ++ks) B[gt][ct][ks] = *(const half8*)(p + ks * 32);
      }
  };
  {
#pragma unroll
    for (int ct = 0; ct < 2; ++ct) {
      const _Float16* p = w_fc + (size_t)(j0 + ct * 16 + l15) * Hh + kbase + quad * 8;
#pragma unroll
      for (int ks = 0; ks < 4; ++ks) Bfc[ct][ks] = *(const half8*)(p + ks * 32);
    }
  }

  auto poll = [&](int tgt) {
    while (1) {
      unsigned v = __hip_atomic_load(pollp, __ATOMIC_RELAXED, __HIP_MEMORY_SCOPE_AGENT);
      if (__all((int)(v >= (unsigned)tgt))) break;
    }
  };

  auto do_step = [&](const _Float16* hsrc, _Float16* hdst, int s) {
    poll(s);
    floatx4 acc[2][4] = {};
    floatx4 f0 = {}, f1 = {};
    const _Float16* ap = hsrc + (size_t)(n0 + l15) * Hh + kbase + quad * 8;
#pragma unroll
    for (int ks = 0; ks < 4; ++ks) {
      half8 a = *(const half8*)(ap + ks * 32);
#pragma unroll
      for (int ct = 0; ct < 2; ++ct)
#pragma unroll
        for (int gt = 0; gt < 4; ++gt)
          acc[ct][gt] =
              __builtin_amdgcn_mfma_f32_16x16x32_f16(a, B[gt][ct][ks], acc[ct][gt], 0, 0, 0);
      if (s >= 1) {  // slot 0 = hT, not an fc input
        f0 = __builtin_amdgcn_mfma_f32_16x16x32_f16(a, Bfc[0][ks], f0, 0, 0, 0);
        f1 = __builtin_amdgcn_mfma_f32_16x16x32_f16(a, Bfc[1][ks], f1, 0, 0, 0);
      }
    }
#pragma unroll
    for (int ct = 0; ct < 2; ++ct)
#pragma unroll
      for (int gt = 0; gt < 4; ++gt) {
        float2 lo, hi;
        lo.x = acc[ct][gt][0]; lo.y = acc[ct][gt][1];
        hi.x = acc[ct][gt][2]; hi.y = acc[ct][gt][3];
        part[wave][ct][gt][0][lane] = lo;
        part[wave][ct][gt][1][lane] = hi;
      }
    if (s >= 1) {
      fcpart[wave][0][lane] = f0;
      fcpart[wave][1][lane] = f1;
    }
    __syncthreads();

    float gv[4];
#pragma unroll
    for (int gt = 0; gt < 4; ++gt) {
      float s2 = bias[gt];
#pragma unroll
      for (int src = 0; src < 8; ++src) {
        float2 p = part[src][oc][gt][rp][lane];
        s2 += rr ? p.y : p.x;
      }
      gv[gt] = s2;
    }
    {
      float ig = fast_sigmoid(gv[0]);
      float fg = fast_sigmoid(gv[1]);
      float gg = fast_tanh(gv[2]);
      float og = fast_sigmoid(gv[3]);
      float c = fg * cst + ig * gg;
      cst = c;
      float h = og * fast_tanh(c);
      int row = n0 + quad * 4 + rp * 2 + rr;
      _Float16 hv = (_Float16)h;
      unsigned short ub;
      __builtin_memcpy(&ub, &hv, 2);
      // agent write-through store (v6-proven); next barrier drains vmcnt.
      __hip_atomic_store((unsigned short*)(hdst + (size_t)row * Hh + j0 + oc * 16 + l15),
                         ub, __ATOMIC_RELAXED, __HIP_MEMORY_SCOPE_AGENT);
    }
    // fc reduce + out store, after the h store so h issues first.
    if (s >= 1) {
      float fsum = bfc;
#pragma unroll
      for (int src = 0; src < 8; ++src) fsum += fcpart[src][fc_half][fc_lsrc][fc_comp];
      out[((size_t)(n0 + fc_row) * TSTEPS + (s - 1)) * DOUT + j0 + fc_col] = fsum;
    }
    __syncthreads();  // drain: all h (and out) stores retired
    if (tid == 0) {
      __hip_atomic_store(&gflags[jb], (unsigned)(s + 1), __ATOMIC_RELAXED,
                         __HIP_MEMORY_SCOPE_AGENT);
    }
  };

  // Step 0: x = hT, hx = 0  =>  gates = hT @ W_ih^T + b_sum
  load_B(w_ih_h);
  do_step(hs, hs + SLOT, 0);
  // Steps 1..255: x = hx = h  =>  gates = h @ (W_ih+W_hh)^T + b_sum
  load_B(w_sum_h);
  for (int s = 1; s < TSTEPS; ++s)
    do_step(hs + (size_t)s * SLOT, hs + (size_t)(s + 1) * SLOT, s);

  // Epilogue: fc for slot 256 (out col 255). Flag 256 stored by all WGs.
  {
    unsigned* ep = gflags + (lane & 31);
    while (1) {
      unsigned v = __hip_atomic_load(ep, __ATOMIC_RELAXED, __HIP_MEMORY_SCOPE_AGENT);
      if (__all((int)(v >= (unsigned)TSTEPS))) break;
    }
    asm volatile("" ::: "memory");
    floatx4 f0 = {}, f1 = {};
    const _Float16* ap =
        hs + (size_t)TSTEPS * SLOT + (size_t)(n0 + l15) * Hh + kbase + quad * 8;
#pragma unroll
    for (int ks = 0; ks < 4; ++ks) {
      half8 a = *(const half8*)(ap + ks * 32);
      f0 = __builtin_amdgcn_mfma_f32_16x16x32_f16(a, Bfc[0][ks], f0, 0, 0, 0);
      f1 = __builtin_amdgcn_mfma_f32_16x16x32_f16(a, Bfc[1][ks], f1, 0, 0, 0);
    }
    fcpart[wave][0][lane] = f0;
    fcpart[wave][1][lane] = f1;
    __syncthreads();
    float fsum = bfc;
#pragma unroll
    for (int src = 0; src < 8; ++src) fsum += fcpart[src][fc_half][fc_lsrc][fc_comp];
    out[((size_t)(n0 + fc_row) * TSTEPS + (TSTEPS - 1)) * DOUT + j0 + fc_col] = fsum;
  }
}

extern "C" void kernel_launch(void* const* d_in, const int* in_sizes, int n_in,
                              void* d_out, int out_size, void* d_ws, size_t ws_size,
                              hipStream_t stream) {
  const float* hT   = (const float*)d_in[0];
  const float* W_ih = (const float*)d_in[1];
  const float* W_hh = (const float*)d_in[2];
  const float* b_ih = (const float*)d_in[3];
  const float* b_hh = (const float*)d_in[4];
  const float* W_fc = (const float*)d_in[5];
  const float* b_fc = (const float*)d_in[6];
  float* out = (float*)d_out;

  char* ws = (char*)d_ws;
  unsigned* flags   = (unsigned*)ws;                    // flags[256] + xcd_ctr[8]
  float* b_sum      = (float*)(ws + 4096);              // 16KB
  _Float16* w_ih_h  = (_Float16*)(ws + 65536);          // 8MB
  _Float16* w_sum_h = w_ih_h + (size_t)4096 * 1024;     // 8MB
  _Float16* w_fc_h  = w_sum_h + (size_t)4096 * 1024;    // 2MB
  _Float16* hs      = w_fc_h + (size_t)1024 * 1024;     // 257 * 256KB = 67.3MB

  prep_kernel<<<4096, 256, 0, stream>>>(W_ih, W_hh, W_fc, b_ih, b_hh, hT,
                                        w_ih_h, w_sum_h, w_fc_h, b_sum, hs, flags);
  lstm_kernel<<<256, 512, 0, stream>>>(w_ih_h, w_sum_h, b_sum, hs, flags,
                                       w_fc_h, b_fc, out);
}